// Round 10
// baseline (309.471 us; speedup 1.0000x reference)
//
#include <hip/hip_runtime.h>
#include <hip/hip_bf16.h>
#include <hip/hip_fp16.h>
#include <math.h>

#define NN 50000
#define EE 800000
#define ET 850000   // EE + NN self loops
#define F1 256      // NHEAD*HID
#define NHEAD 8
#define HID 32
#define NCLASS 40
#define NEG 0.2f

#define NB_HIST ((ET + 255) / 256)     // 3321
#define NB_PREP 320
#define NB_G1   ((NN + 127) / 128)     // 391
#define NB_SCAN ((NN + 1023) / 1024)   // 49

typedef __attribute__((ext_vector_type(8))) _Float16 half8_t;   // 8 fp16 (4 VGPRs)
typedef __attribute__((ext_vector_type(4))) float float4_t;     // MFMA C/D

__device__ __forceinline__ int clampN(int v) {
    return v < 0 ? 0 : (v >= NN ? NN - 1 : v);
}
__device__ __forceinline__ unsigned short f2h(float f) {
    __half h = __float2half(f);
    return __builtin_bit_cast(unsigned short, h);
}
__device__ __forceinline__ float h2f(unsigned short u) {
    __half h = __builtin_bit_cast(__half, u);
    return __half2float(h);
}
__device__ __forceinline__ float hlo2f(unsigned int u) {
    return h2f((unsigned short)(u & 0xFFFFu));
}
__device__ __forceinline__ float hhi2f(unsigned int u) {
    return h2f((unsigned short)(u >> 16));
}

// ---------------- fusedA: prep (blocks 0..319) ∥ hist (blocks 320..) ----------------
__global__ __launch_bounds__(256) void fusedA_kernel(const int* __restrict__ ei, int* __restrict__ deg,
                                                     unsigned int* __restrict__ pack,
                                                     const float* __restrict__ W1,
                                                     const float* __restrict__ as1, const float* __restrict__ ad1,
                                                     const float* __restrict__ W2,
                                                     const float* __restrict__ ats2, const float* __restrict__ atd2,
                                                     unsigned short* __restrict__ Bt1,
                                                     unsigned short* __restrict__ Bt2) {
    int blk = blockIdx.x;
    if (blk < NB_PREP) {
        int n = blk;
        int k = threadIdx.x;     // 0..255
        if (n < 272) {
            float v;
            if (n < 256) {
                v = W1[(size_t)k * 256 + n];
            } else {
                int j = n - 256;
                int h = j & 7;
                const float* att = (j < 8) ? (as1 + h * 32) : (ad1 + h * 32);
                float s = 0.f;
                #pragma unroll
                for (int c = 0; c < 32; ++c) s += W1[(size_t)k * 256 + h * 32 + c] * att[c];
                v = s;
            }
            Bt1[n * 256 + k] = f2h(v);
        } else {
            int n2 = n - 272;    // 0..47
            float v = 0.f;
            if (n2 < NCLASS) {
                v = W2[(size_t)k * NCLASS + n2];
            } else if (n2 == NCLASS) {
                #pragma unroll
                for (int j = 0; j < NCLASS; ++j) v += W2[(size_t)k * NCLASS + j] * ats2[j];
            } else if (n2 == NCLASS + 1) {
                #pragma unroll
                for (int j = 0; j < NCLASS; ++j) v += W2[(size_t)k * NCLASS + j] * atd2[j];
            }
            Bt2[n2 * 256 + k] = f2h(v);
        }
    } else {
        int t = (blk - NB_PREP) * 256 + threadIdx.x;
        if (t >= ET) return;
        int d = (t < EE) ? ei[EE + t] : (t - EE);
        d = clampN(d);
        int r = atomicAdd(&deg[d], 1);
        pack[t] = ((unsigned)d << 15) | (unsigned)r;
    }
}

// ---------------- single-launch decoupled-lookback scan ----------------
// 49 blocks on 256 CUs are always co-resident -> spin on predecessors is
// deadlock-free. flags[b] packs (value<<2)|state; state 1 = block aggregate,
// state 2 = inclusive prefix. Device-scope atomics carry the value in the
// same word, so no separate fence is required.
__global__ __launch_bounds__(256) void scan_kernel(const int* __restrict__ deg, int* __restrict__ off,
                                                   unsigned long long* __restrict__ flags) {
    __shared__ int lds[256];
    __shared__ int s_prefix;
    int b = blockIdx.x, tid = threadIdx.x;
    int base = b * 1024 + tid * 4;
    int v0 = (base + 0 < NN) ? deg[base + 0] : 0;
    int v1 = (base + 1 < NN) ? deg[base + 1] : 0;
    int v2 = (base + 2 < NN) ? deg[base + 2] : 0;
    int v3 = (base + 3 < NN) ? deg[base + 3] : 0;
    int s1 = v0 + v1, s2 = s1 + v2, s3 = s2 + v3;
    lds[tid] = s3;
    __syncthreads();
    for (int o = 1; o < 256; o <<= 1) {
        int t = (tid >= o) ? lds[tid - o] : 0;
        __syncthreads();
        if (tid >= o) lds[tid] += t;
        __syncthreads();
    }
    if (tid == 0) {
        unsigned long long total = (unsigned long long)(unsigned)lds[255];
        atomicExch(&flags[b], (total << 2) | 1ULL);          // publish aggregate
        unsigned long long prefix = 0;
        int i = b - 1;
        while (i >= 0) {
            unsigned long long f;
            do { f = atomicAdd(&flags[i], 0ULL); } while ((f & 3ULL) == 0ULL);
            prefix += (f >> 2);
            if ((f & 3ULL) == 2ULL) break;                   // inclusive found
            --i;
        }
        atomicExch(&flags[b], ((total + prefix) << 2) | 2ULL); // publish inclusive
        s_prefix = (int)prefix;
        if (b == 0) off[0] = 0;
    }
    __syncthreads();
    int add = s_prefix;
    int excl = (tid ? lds[tid - 1] : 0) + add;
    if (base + 0 < NN) off[base + 1] = excl + v0;
    if (base + 1 < NN) off[base + 2] = excl + s1;
    if (base + 2 < NN) off[base + 3] = excl + s2;
    if (base + 3 < NN) off[base + 4] = excl + s3;
}

// ---------------- fusedB: gemm1 (blocks 0..390) ∥ scatter (blocks 391..) ----------------
#define AKP 40
__global__ __launch_bounds__(256, 2) void fusedB_kernel(const float* __restrict__ x,
                                                        const unsigned short* __restrict__ Bt,
                                                        unsigned short* __restrict__ h1b,
                                                        float* __restrict__ asrc1, float* __restrict__ adst1,
                                                        const int* __restrict__ ei, const int* __restrict__ off,
                                                        const unsigned int* __restrict__ pack, int* __restrict__ esrc) {
    __shared__ __align__(16) unsigned short Ah[128 * AKP];
    __shared__ __align__(16) unsigned short Bs[272 * AKP];
    if (blockIdx.x >= NB_G1) {
        // ---- scatter role ----
        int t = (blockIdx.x - NB_G1) * 256 + threadIdx.x;
        if (t >= ET) return;
        unsigned p = pack[t];
        int d = p >> 15;
        int r = p & 0x7FFF;
        int s = (t < EE) ? ei[t] : (t - EE);
        s = clampN(s);
        esrc[off[d] + r] = s;
        return;
    }
    // ---- gemm1 role ----
    int tid = threadIdx.x;
    int wave = tid >> 6, lane = tid & 63;
    int quad = lane >> 4, l16 = lane & 15;
    int row0 = blockIdx.x * 128;

    float4_t acc[2][17];
    #pragma unroll
    for (int i = 0; i < 2; ++i)
        #pragma unroll
        for (int j = 0; j < 17; ++j) acc[i][j] = (float4_t){0.f, 0.f, 0.f, 0.f};

    for (int k0 = 0; k0 < 256; k0 += 32) {
        __syncthreads();
        #pragma unroll
        for (int i = 0; i < 4; ++i) {
            int id = i * 256 + tid;
            int r = id >> 3, kq = id & 7;
            int rr = row0 + r; if (rr >= NN) rr = NN - 1;
            float4 v = *(const float4*)(x + (size_t)rr * 256 + k0 + kq * 4);
            ushort4 hi;
            hi.x = f2h(v.x);
            hi.y = f2h(v.y);
            hi.z = f2h(v.z);
            hi.w = f2h(v.w);
            *(ushort4*)(Ah + r * AKP + kq * 4) = hi;
        }
        for (int id = tid; id < 272 * 4; id += 256) {
            int r = id >> 2, kq = id & 3;
            *(float4*)(Bs + r * AKP + kq * 8) = *(const float4*)(Bt + (size_t)r * 256 + k0 + kq * 8);
        }
        __syncthreads();
        half8_t ah[2];
        #pragma unroll
        for (int mt = 0; mt < 2; ++mt) {
            int mrow = wave * 32 + mt * 16 + l16;
            ah[mt] = *(const half8_t*)(Ah + mrow * AKP + quad * 8);
        }
        #pragma unroll
        for (int nt = 0; nt < 17; ++nt) {
            int nrow = nt * 16 + l16;
            half8_t bh = *(const half8_t*)(Bs + nrow * AKP + quad * 8);
            #pragma unroll
            for (int mt = 0; mt < 2; ++mt) {
                acc[mt][nt] = __builtin_amdgcn_mfma_f32_16x16x32_f16(ah[mt], bh, acc[mt][nt], 0, 0, 0);
            }
        }
    }
    #pragma unroll
    for (int mt = 0; mt < 2; ++mt) {
        int rbase = row0 + wave * 32 + mt * 16 + quad * 4;
        #pragma unroll
        for (int r = 0; r < 4; ++r) {
            int row = rbase + r;
            if (row >= NN) continue;
            #pragma unroll
            for (int nt = 0; nt < 16; ++nt)
                h1b[(size_t)row * 256 + nt * 16 + l16] = f2h(acc[mt][nt][r]);
            float v = acc[mt][16][r];
            if (l16 < 8) asrc1[row * 8 + l16] = v;
            else         adst1[row * 8 + (l16 - 8)] = v;
        }
    }
}

// ---------------- layer-1 aggregation: no-max softmax (best measured: 67us) ----------------
#define WST 68
__global__ __launch_bounds__(256) void agg1_kernel(const unsigned short* __restrict__ h1b, const float* __restrict__ asrc,
                                                   const float* __restrict__ adst, const int* __restrict__ esrc,
                                                   const int* __restrict__ off,
                                                   const float* __restrict__ b1, unsigned short* __restrict__ hout) {
    __shared__ __align__(16) float wl[4][8 * WST];
    __shared__ __align__(16) int  snl[4][64];
    int tid = threadIdx.x;
    int wave = tid >> 6;
    int wid = blockIdx.x * 4 + wave;
    if (wid >= NN) return;
    int lane = tid & 63;
    int hp = lane & 7;        // phase head
    int jp = lane >> 3;       // phase edge slot
    int hc = lane >> 3;       // channel head
    int c0 = lane * 4;        // channels owned
    float* wlw = wl[wave];
    int* snw = snl[wave];
    const float* wrow = wlw + hc * WST;
    const char* hb = (const char*)h1b;
    unsigned lofs = (unsigned)c0 * 2;   // lane byte offset within a row
    float adh_p = adst[wid * 8 + hp];
    int e0 = off[wid], e1 = off[wid + 1];

    float s = 0.f;
    float ax = 0.f, ay = 0.f, az = 0.f, aw = 0.f;

    for (int base = e0; base < e1; base += 64) {
        int cnt = e1 - base; if (cnt > 64) cnt = 64;
        int snv = esrc[base + (lane < cnt ? lane : cnt - 1)];
        snw[lane] = snv;
        int nch = (cnt + 7) >> 3;
        // ---- weights straight to LDS (no max pass); w=0 for padded slots ----
        #pragma unroll
        for (int cj = 0; cj < 8; ++cj) {
            if (cj >= nch) break;
            int jedge = cj * 8 + jp;
            int sj = __shfl(snv, jedge);
            float a = asrc[sj * 8 + hp];
            float e = a + adh_p;
            e = (e >= 0.f) ? e : NEG * e;
            float w = (jedge < cnt) ? __expf(e) : 0.f;
            s += w;
            wlw[hp * WST + cj * 8 + jp] = w;
        }
        // ---- gather: scalar row bases, 8 edges in flight ----
        int nslots = nch * 8;
        for (int j = 0; j < nslots; j += 8) {
            float4 wa = *(const float4*)(wrow + j);
            float4 wb = *(const float4*)(wrow + j + 4);
            int4 sa = *(const int4*)(snw + j);
            int4 sb = *(const int4*)(snw + j + 4);
            const char* r0 = hb + ((size_t)(unsigned)__builtin_amdgcn_readfirstlane(sa.x) << 9);
            const char* r1 = hb + ((size_t)(unsigned)__builtin_amdgcn_readfirstlane(sa.y) << 9);
            const char* r2 = hb + ((size_t)(unsigned)__builtin_amdgcn_readfirstlane(sa.z) << 9);
            const char* r3 = hb + ((size_t)(unsigned)__builtin_amdgcn_readfirstlane(sa.w) << 9);
            const char* r4 = hb + ((size_t)(unsigned)__builtin_amdgcn_readfirstlane(sb.x) << 9);
            const char* r5 = hb + ((size_t)(unsigned)__builtin_amdgcn_readfirstlane(sb.y) << 9);
            const char* r6 = hb + ((size_t)(unsigned)__builtin_amdgcn_readfirstlane(sb.z) << 9);
            const char* r7 = hb + ((size_t)(unsigned)__builtin_amdgcn_readfirstlane(sb.w) << 9);
            uint2 u0 = *(const uint2*)(r0 + lofs);
            uint2 u1 = *(const uint2*)(r1 + lofs);
            uint2 u2 = *(const uint2*)(r2 + lofs);
            uint2 u3 = *(const uint2*)(r3 + lofs);
            uint2 u4 = *(const uint2*)(r4 + lofs);
            uint2 u5 = *(const uint2*)(r5 + lofs);
            uint2 u6 = *(const uint2*)(r6 + lofs);
            uint2 u7 = *(const uint2*)(r7 + lofs);
            ax += wa.x * hlo2f(u0.x);
            ay += wa.x * hhi2f(u0.x);
            az += wa.x * hlo2f(u0.y);
            aw += wa.x * hhi2f(u0.y);
            ax += wa.y * hlo2f(u1.x);
            ay += wa.y * hhi2f(u1.x);
            az += wa.y * hlo2f(u1.y);
            aw += wa.y * hhi2f(u1.y);
            ax += wa.z * hlo2f(u2.x);
            ay += wa.z * hhi2f(u2.x);
            az += wa.z * hlo2f(u2.y);
            aw += wa.z * hhi2f(u2.y);
            ax += wa.w * hlo2f(u3.x);
            ay += wa.w * hhi2f(u3.x);
            az += wa.w * hlo2f(u3.y);
            aw += wa.w * hhi2f(u3.y);
            ax += wb.x * hlo2f(u4.x);
            ay += wb.x * hhi2f(u4.x);
            az += wb.x * hlo2f(u4.y);
            aw += wb.x * hhi2f(u4.y);
            ax += wb.y * hlo2f(u5.x);
            ay += wb.y * hhi2f(u5.x);
            az += wb.y * hlo2f(u5.y);
            aw += wb.y * hhi2f(u5.y);
            ax += wb.z * hlo2f(u6.x);
            ay += wb.z * hhi2f(u6.x);
            az += wb.z * hlo2f(u6.y);
            aw += wb.z * hhi2f(u6.y);
            ax += wb.w * hlo2f(u7.x);
            ay += wb.w * hhi2f(u7.x);
            az += wb.w * hlo2f(u7.y);
            aw += wb.w * hhi2f(u7.y);
        }
    }
    s += __shfl_xor(s, 8);
    s += __shfl_xor(s, 16);
    s += __shfl_xor(s, 32);
    float sh = __shfl(s, hc);
    float inv = 1.f / (sh + 1e-16f);
    float4 b = *(const float4*)(b1 + c0);
    float vx = ax * inv + b.x, vy = ay * inv + b.y, vz = az * inv + b.z, vw = aw * inv + b.w;
    ushort4 o;
    o.x = f2h((vx > 0.f) ? vx : expm1f(vx));
    o.y = f2h((vy > 0.f) ? vy : expm1f(vy));
    o.z = f2h((vz > 0.f) ? vz : expm1f(vz));
    o.w = f2h((vw > 0.f) ? vw : expm1f(vw));
    *(ushort4*)(hout + (size_t)wid * 256 + c0) = o;
}

// ---------------- GEMM2 (MFMA fp16): h[NN][256] @ W2t, alpha cols folded ----------------
// 14KB LDS, low VGPR -> allow 4 blocks/CU (16 waves) for streaming-read TLP.
#define BKP 40
__global__ __launch_bounds__(256, 4) void gemm2_kernel(const unsigned short* __restrict__ h,
                                                       const unsigned short* __restrict__ Bt2,
                                                       unsigned short* __restrict__ h2b, float* __restrict__ as2,
                                                       float* __restrict__ ad2) {
    __shared__ __align__(16) unsigned short Ah[128 * BKP];
    __shared__ __align__(16) unsigned short Bs[48 * BKP];
    int tid = threadIdx.x;
    int wave = tid >> 6, lane = tid & 63;
    int quad = lane >> 4, l16 = lane & 15;
    int row0 = blockIdx.x * 128;

    float4_t acc[2][3];
    #pragma unroll
    for (int i = 0; i < 2; ++i)
        #pragma unroll
        for (int j = 0; j < 3; ++j) acc[i][j] = (float4_t){0.f, 0.f, 0.f, 0.f};

    for (int k0 = 0; k0 < 256; k0 += 32) {
        __syncthreads();
        #pragma unroll
        for (int i = 0; i < 2; ++i) {
            int id = i * 256 + tid;       // 0..511
            int r = id >> 2, kq = id & 3; // r 0..127, kq 0..3 (8 halves)
            int rr = row0 + r; if (rr >= NN) rr = NN - 1;
            *(float4*)(Ah + r * BKP + kq * 8) = *(const float4*)(h + (size_t)rr * 256 + k0 + kq * 8);
        }
        if (tid < 192) {
            int r = tid >> 2, kq = tid & 3;  // r 0..47
            *(float4*)(Bs + r * BKP + kq * 8) = *(const float4*)(Bt2 + (size_t)r * 256 + k0 + kq * 8);
        }
        __syncthreads();
        half8_t ah[2];
        #pragma unroll
        for (int mt = 0; mt < 2; ++mt) {
            int mrow = wave * 32 + mt * 16 + l16;
            ah[mt] = *(const half8_t*)(Ah + mrow * BKP + quad * 8);
        }
        #pragma unroll
        for (int nt = 0; nt < 3; ++nt) {
            int nrow = nt * 16 + l16;
            half8_t bh = *(const half8_t*)(Bs + nrow * BKP + quad * 8);
            #pragma unroll
            for (int mt = 0; mt < 2; ++mt) {
                acc[mt][nt] = __builtin_amdgcn_mfma_f32_16x16x32_f16(ah[mt], bh, acc[mt][nt], 0, 0, 0);
            }
        }
    }
    #pragma unroll
    for (int mt = 0; mt < 2; ++mt) {
        int rbase = row0 + wave * 32 + mt * 16 + quad * 4;
        #pragma unroll
        for (int r = 0; r < 4; ++r) {
            int row = rbase + r;
            if (row >= NN) continue;
            #pragma unroll
            for (int nt = 0; nt < 3; ++nt) {
                int j = nt * 16 + l16;
                float v = acc[mt][nt][r];
                if (j < NCLASS)            h2b[(size_t)row * 40 + j] = f2h(v);
                else if (j == NCLASS)      as2[row] = v;
                else if (j == NCLASS + 1)  ad2[row] = v;
            }
        }
    }
}

// ---------------- layer-2 aggregation: no-max softmax, 16-deep gather ----------------
__global__ __launch_bounds__(256) void agg2_kernel(const unsigned short* __restrict__ h2b, const float* __restrict__ asrc,
                                                   const float* __restrict__ adst, const int* __restrict__ esrc,
                                                   const int* __restrict__ off,
                                                   const float* __restrict__ b2, float* __restrict__ outF,
                                                   float* __restrict__ outL) {
    __shared__ __align__(16) float wl2[4][64];
    __shared__ __align__(16) int  snl2[4][64];
    int tid = threadIdx.x;
    int wave = tid >> 6;
    int wid = blockIdx.x * 4 + wave;
    if (wid >= NN) return;
    int lane = tid & 63;
    int c = lane;
    const char* hb = (const char*)h2b;
    unsigned coff = (unsigned)(c < NCLASS ? c : 0) * 2;
    float* wlw = wl2[wave];
    int* snw = snl2[wave];
    float bc = (c < NCLASS) ? b2[c] : 0.f;
    float adh = adst[wid];
    int e0 = off[wid], e1 = off[wid + 1];

    float s = 0.f, acc = 0.f;

    for (int base = e0; base < e1; base += 64) {
        int cnt = e1 - base; if (cnt > 64) cnt = 64;
        int snv = esrc[base + (lane < cnt ? lane : cnt - 1)];
        snw[lane] = snv;
        float a = asrc[snv];
        float e = a + adh;
        e = (e >= 0.f) ? e : NEG * e;
        float w = (lane < cnt) ? __expf(e) : 0.f;   // w=0 for padded lanes
        s += w;
        wlw[lane] = w;
        int n16 = (cnt + 15) & ~15;
        for (int j = 0; j < n16; j += 16) {
            float4 wa = *(const float4*)(wlw + j);
            float4 wb = *(const float4*)(wlw + j + 4);
            float4 wc = *(const float4*)(wlw + j + 8);
            float4 wd = *(const float4*)(wlw + j + 12);
            int4 sa = *(const int4*)(snw + j);
            int4 sb = *(const int4*)(snw + j + 4);
            int4 sc = *(const int4*)(snw + j + 8);
            int4 sd = *(const int4*)(snw + j + 12);
            const char* r0 = hb + (size_t)((unsigned)__builtin_amdgcn_readfirstlane(sa.x) * 80u);
            const char* r1 = hb + (size_t)((unsigned)__builtin_amdgcn_readfirstlane(sa.y) * 80u);
            const char* r2 = hb + (size_t)((unsigned)__builtin_amdgcn_readfirstlane(sa.z) * 80u);
            const char* r3 = hb + (size_t)((unsigned)__builtin_amdgcn_readfirstlane(sa.w) * 80u);
            const char* r4 = hb + (size_t)((unsigned)__builtin_amdgcn_readfirstlane(sb.x) * 80u);
            const char* r5 = hb + (size_t)((unsigned)__builtin_amdgcn_readfirstlane(sb.y) * 80u);
            const char* r6 = hb + (size_t)((unsigned)__builtin_amdgcn_readfirstlane(sb.z) * 80u);
            const char* r7 = hb + (size_t)((unsigned)__builtin_amdgcn_readfirstlane(sb.w) * 80u);
            const char* r8 = hb + (size_t)((unsigned)__builtin_amdgcn_readfirstlane(sc.x) * 80u);
            const char* r9 = hb + (size_t)((unsigned)__builtin_amdgcn_readfirstlane(sc.y) * 80u);
            const char* rA = hb + (size_t)((unsigned)__builtin_amdgcn_readfirstlane(sc.z) * 80u);
            const char* rB = hb + (size_t)((unsigned)__builtin_amdgcn_readfirstlane(sc.w) * 80u);
            const char* rC = hb + (size_t)((unsigned)__builtin_amdgcn_readfirstlane(sd.x) * 80u);
            const char* rD = hb + (size_t)((unsigned)__builtin_amdgcn_readfirstlane(sd.y) * 80u);
            const char* rE = hb + (size_t)((unsigned)__builtin_amdgcn_readfirstlane(sd.z) * 80u);
            const char* rF = hb + (size_t)((unsigned)__builtin_amdgcn_readfirstlane(sd.w) * 80u);
            unsigned short v0 = *(const unsigned short*)(r0 + coff);
            unsigned short v1 = *(const unsigned short*)(r1 + coff);
            unsigned short v2 = *(const unsigned short*)(r2 + coff);
            unsigned short v3 = *(const unsigned short*)(r3 + coff);
            unsigned short v4 = *(const unsigned short*)(r4 + coff);
            unsigned short v5 = *(const unsigned short*)(r5 + coff);
            unsigned short v6 = *(const unsigned short*)(r6 + coff);
            unsigned short v7 = *(const unsigned short*)(r7 + coff);
            unsigned short v8 = *(const unsigned short*)(r8 + coff);
            unsigned short v9 = *(const unsigned short*)(r9 + coff);
            unsigned short vA = *(const unsigned short*)(rA + coff);
            unsigned short vB = *(const unsigned short*)(rB + coff);
            unsigned short vC = *(const unsigned short*)(rC + coff);
            unsigned short vD = *(const unsigned short*)(rD + coff);
            unsigned short vE = *(const unsigned short*)(rE + coff);
            unsigned short vF = *(const unsigned short*)(rF + coff);
            acc += wa.x * h2f(v0);
            acc += wa.y * h2f(v1);
            acc += wa.z * h2f(v2);
            acc += wa.w * h2f(v3);
            acc += wb.x * h2f(v4);
            acc += wb.y * h2f(v5);
            acc += wb.z * h2f(v6);
            acc += wb.w * h2f(v7);
            acc += wc.x * h2f(v8);
            acc += wc.y * h2f(v9);
            acc += wc.z * h2f(vA);
            acc += wc.w * h2f(vB);
            acc += wd.x * h2f(vC);
            acc += wd.y * h2f(vD);
            acc += wd.z * h2f(vE);
            acc += wd.w * h2f(vF);
        }
    }
    s += __shfl_xor(s, 1);
    s += __shfl_xor(s, 2);
    s += __shfl_xor(s, 4);
    s += __shfl_xor(s, 8);
    s += __shfl_xor(s, 16);
    s += __shfl_xor(s, 32);
    float inv = 1.f / (s + 1e-16f);
    float fin = (c < NCLASS) ? (acc * inv + bc) : -INFINITY;
    if (c < NCLASS) outF[(size_t)wid * 40 + c] = fin;
    float mx = fin;
    for (int o = 32; o; o >>= 1) mx = fmaxf(mx, __shfl_xor(mx, o));
    float ex = (c < NCLASS) ? __expf(fin - mx) : 0.f;
    float sm = ex;
    for (int o = 32; o; o >>= 1) sm += __shfl_xor(sm, o);
    if (c < NCLASS) outL[(size_t)wid * 40 + c] = fin - mx - __logf(sm);
}

extern "C" void kernel_launch(void* const* d_in, const int* in_sizes, int n_in,
                              void* d_out, int out_size, void* d_ws, size_t ws_size,
                              hipStream_t stream) {
    const float* x   = (const float*)d_in[0];
    const int*   ei  = (const int*)d_in[1];
    const float* W1  = (const float*)d_in[3];
    const float* as1 = (const float*)d_in[4];
    const float* ad1 = (const float*)d_in[5];
    const float* b1  = (const float*)d_in[6];
    const float* W2  = (const float*)d_in[7];
    const float* as2c = (const float*)d_in[8];
    const float* ad2c = (const float*)d_in[9];
    const float* b2  = (const float*)d_in[10];

    float* outF = (float*)d_out;
    float* outL = outF + (size_t)NN * NCLASS;

    char* w = (char*)d_ws;
    auto alloc = [&](size_t bytes) {
        void* p = (void*)w;
        w += (bytes + 255) & ~(size_t)255;
        return p;
    };
    unsigned short* h1b = (unsigned short*)alloc((size_t)NN * 256 * 2);
    unsigned short* hbuf = (unsigned short*)alloc((size_t)NN * 256 * 2);
    unsigned short* h2b = (unsigned short*)alloc((size_t)NN * 40 * 2);
    float* asrc1 = (float*)alloc((size_t)NN * 8 * 4);
    float* adst1 = (float*)alloc((size_t)NN * 8 * 4);
    float* asrc2 = (float*)alloc((size_t)NN * 4);
    float* adst2 = (float*)alloc((size_t)NN * 4);
    int* deg    = (int*)alloc((size_t)NN * 4);        // zeroed below (contiguous with flags)
    unsigned long long* flags = (unsigned long long*)alloc(64 * 8);  // scan lookback state
    int* off    = (int*)alloc((size_t)(NN + 1) * 4);
    unsigned int* pack = (unsigned int*)alloc((size_t)ET * 4);
    int* esrc   = (int*)alloc((size_t)ET * 4);
    unsigned short* W1th = (unsigned short*)alloc((size_t)272 * 256 * 2);
    unsigned short* W2t  = (unsigned short*)alloc((size_t)48 * 256 * 2);

    // deg region (rounded to 256) and flags are contiguous: one memset covers both.
    size_t degRounded = (((size_t)NN * 4) + 255) & ~(size_t)255;
    hipMemsetAsync(deg, 0, degRounded + 64 * 8, stream);

    fusedA_kernel<<<NB_PREP + NB_HIST, 256, 0, stream>>>(ei, deg, pack, W1, as1, ad1, W2, as2c, ad2c, W1th, W2t);
    scan_kernel<<<NB_SCAN, 256, 0, stream>>>(deg, off, flags);
    fusedB_kernel<<<NB_G1 + NB_HIST, 256, 0, stream>>>(x, W1th, h1b, asrc1, adst1, ei, off, pack, esrc);
    agg1_kernel<<<(NN + 3) / 4, 256, 0, stream>>>(h1b, asrc1, adst1, esrc, off, b1, hbuf);
    gemm2_kernel<<<(NN + 127) / 128, 256, 0, stream>>>(hbuf, W2t, h2b, asrc2, adst2);
    agg2_kernel<<<(NN + 3) / 4, 256, 0, stream>>>(h2b, asrc2, adst2, esrc, off, b2, outF, outL);
}